// Round 1
// baseline (894.642 us; speedup 1.0000x reference)
//
#include <hip/hip_runtime.h>

typedef __bf16 bf16;
typedef __bf16 bf16x8 __attribute__((ext_vector_type(8)));
typedef __bf16 bf16x4 __attribute__((ext_vector_type(4)));
typedef float  f32x4  __attribute__((ext_vector_type(4)));

#define SEQ     2048
#define HIDDEN  3584
#define NHEADS  28
#define NKV     4
#define HD      128
#define SCALING 0.08838834764831845f
#define L2E     1.44269504088896341f

typedef __attribute__((address_space(1))) void gvoid;
typedef __attribute__((address_space(3))) void lvoid;

__device__ __forceinline__ void gl_lds16(const void* g, void* l) {
  __builtin_amdgcn_global_load_lds((gvoid*)g, (lvoid*)l, 16, 0, 0);
}

// ---------------- fp32 -> bf16 convert ----------------
__global__ void f2bf_kernel(const float* __restrict__ in, bf16* __restrict__ out, int n8) {
  int i = blockIdx.x * 256 + threadIdx.x;
  if (i >= n8) return;
  const f32x4* p = (const f32x4*)(in + (size_t)i * 8);
  f32x4 x = p[0], y = p[1];
  bf16x8 o;
  o[0] = (bf16)x[0]; o[1] = (bf16)x[1]; o[2] = (bf16)x[2]; o[3] = (bf16)x[3];
  o[4] = (bf16)y[0]; o[5] = (bf16)y[1]; o[6] = (bf16)y[2]; o[7] = (bf16)y[3];
  *(bf16x8*)(out + (size_t)i * 8) = o;
}

// ---------------- NT GEMM: C[m][n] = sum_k A[m][k] * W[n][k] (+bias) ----------------
// MODE 0: plain fp32 out [M][3584] (output projection, no bias)
// MODE 1: fused QKV, N=4608; scatter bf16 into Q[B,28,S,128] / K,V[B,4,S,128] with bias
template <int MODE>
__global__ __launch_bounds__(256, 2) void gemm_kernel(
    const bf16* __restrict__ A,
    const bf16* __restrict__ W0, const bf16* __restrict__ W1, const bf16* __restrict__ W2,
    const float* __restrict__ b0, const float* __restrict__ b1, const float* __restrict__ b2,
    float* __restrict__ outF,
    bf16* __restrict__ Qb, bf16* __restrict__ Kb, bf16* __restrict__ Vb) {
  __shared__ bf16 As[128 * 32];
  __shared__ bf16 Bs[128 * 32];
  const int tid = threadIdx.x;
  const int w = tid >> 6, lane = tid & 63;
  const int wm = (w >> 1) * 64, wn = (w & 1) * 64;
  const int m0 = blockIdx.y * 128;
  const int n0 = blockIdx.x * 128;
  const int K = HIDDEN;

  const bf16* Bsrc;
  int nbase;
  if (MODE == 0) { Bsrc = W0; nbase = 0; }
  else {
    if (n0 < 3584)      { Bsrc = W0; nbase = 0; }
    else if (n0 < 4096) { Bsrc = W1; nbase = 3584; }
    else                { Bsrc = W2; nbase = 4096; }
  }
  const int bn0 = n0 - nbase;

  f32x4 acc[4][4];
#pragma unroll
  for (int i = 0; i < 4; i++)
#pragma unroll
    for (int j = 0; j < 4; j++) { f32x4 z = {0.f, 0.f, 0.f, 0.f}; acc[i][j] = z; }

  const int srow = lane >> 2;          // 0..15 within 1KB chunk
  const int scol = (lane & 3) * 8;     // element col offset
  const int mr = lane & 15, kq = (lane >> 4) * 8;

  for (int k0 = 0; k0 < K; k0 += 32) {
    __syncthreads();
#pragma unroll
    for (int c = 0; c < 2; c++) {
      int chunk = w * 2 + c;
      int row = chunk * 16 + srow;
      gl_lds16(&A[(size_t)(m0 + row) * K + k0 + scol], &As[chunk * 512]);
      gl_lds16(&Bsrc[(size_t)(bn0 + row) * K + k0 + scol], &Bs[chunk * 512]);
    }
    __syncthreads();
    bf16x8 a[4], b[4];
#pragma unroll
    for (int i = 0; i < 4; i++) a[i] = *(const bf16x8*)&As[(wm + i * 16 + mr) * 32 + kq];
#pragma unroll
    for (int j = 0; j < 4; j++) b[j] = *(const bf16x8*)&Bs[(wn + j * 16 + mr) * 32 + kq];
#pragma unroll
    for (int i = 0; i < 4; i++)
#pragma unroll
      for (int j = 0; j < 4; j++)
        acc[i][j] = __builtin_amdgcn_mfma_f32_16x16x32_bf16(a[i], b[j], acc[i][j], 0, 0, 0);
  }

  const int quad = lane >> 4, col = lane & 15;
  if (MODE == 0) {
#pragma unroll
    for (int i = 0; i < 4; i++)
#pragma unroll
      for (int j = 0; j < 4; j++) {
        int n = n0 + wn + j * 16 + col;
#pragma unroll
        for (int r = 0; r < 4; r++) {
          int m = m0 + wm + i * 16 + quad * 4 + r;
          outF[(size_t)m * 3584 + n] = acc[i][j][r];
        }
      }
  } else {
    bf16* dst; int H; const float* bias;
    if (n0 < 3584)      { dst = Qb; H = NHEADS; bias = b0; }
    else if (n0 < 4096) { dst = Kb; H = NKV;    bias = b1; }
    else                { dst = Vb; H = NKV;    bias = b2; }
#pragma unroll
    for (int j = 0; j < 4; j++) {
      int nl = bn0 + wn + j * 16 + col;
      float bb = bias[nl];
      int hh = nl >> 7, d = nl & 127;
#pragma unroll
      for (int i = 0; i < 4; i++)
#pragma unroll
        for (int r = 0; r < 4; r++) {
          int m = m0 + wm + i * 16 + quad * 4 + r;
          int bidx = m >> 11, s = m & 2047;
          dst[(((size_t)bidx * H + hh) * SEQ + s) * HD + d] = (bf16)(acc[i][j][r] + bb);
        }
    }
  }
}

// ---------------- RoPE (in place, bf16) ----------------
__global__ void rope_kernel(bf16* __restrict__ X, const float* __restrict__ cosp,
                            const float* __restrict__ sinp, int nheads) {
  int idx = blockIdx.x * 256 + threadIdx.x;
  int dg = idx & 15;            // d = dg*4 in [0,64)
  int s = (idx >> 4) & 2047;
  int bh = idx >> 15;
  int b = bh / nheads;
  int d = dg * 4;
  f32x4 c = *(const f32x4*)&cosp[((size_t)b * SEQ + s) * HD + d];
  f32x4 sn = *(const f32x4*)&sinp[((size_t)b * SEQ + s) * HD + d];
  bf16* p = X + ((size_t)bh * SEQ + s) * HD + d;
  bf16x4 lo = *(bf16x4*)p;
  bf16x4 hi = *(bf16x4*)(p + 64);
  bf16x4 nlo, nhi;
#pragma unroll
  for (int i = 0; i < 4; i++) {
    float l = (float)lo[i], h = (float)hi[i];
    nlo[i] = (bf16)(l * c[i] - h * sn[i]);
    nhi[i] = (bf16)(h * c[i] + l * sn[i]);
  }
  *(bf16x4*)p = nlo;
  *(bf16x4*)(p + 64) = nhi;
}

// ---------------- V transpose per head: [S][D] -> [D][S] ----------------
__global__ void transpose_kernel(const bf16* __restrict__ V, bf16* __restrict__ Vt) {
  __shared__ bf16 t[32][33];
  int head = blockIdx.z;
  int s0 = blockIdx.x * 32, d0 = blockIdx.y * 32;
  const bf16* src = V + (size_t)head * SEQ * HD;
  bf16* dst = Vt + (size_t)head * HD * SEQ;
#pragma unroll
  for (int i = 0; i < 4; i++)
    t[threadIdx.y + i * 8][threadIdx.x] =
        src[(size_t)(s0 + threadIdx.y + i * 8) * HD + d0 + threadIdx.x];
  __syncthreads();
#pragma unroll
  for (int i = 0; i < 4; i++)
    dst[(size_t)(d0 + threadIdx.y + i * 8) * SEQ + s0 + threadIdx.x] =
        t[threadIdx.x][threadIdx.y + i * 8];
}

// ---------------- Flash attention ----------------
// grid (S/64, 28, 2); block 256 = 4 waves; wave w owns q rows [q0+16w, q0+16w+16)
__global__ __launch_bounds__(256, 2) void flash_kernel(
    const bf16* __restrict__ Q, const bf16* __restrict__ K,
    const bf16* __restrict__ Vt, bf16* __restrict__ attn) {
  __shared__ bf16 Qs[64 * 136];      // [qrow][d], padded
  __shared__ bf16 Ks[64 * 136];      // [key][d], padded
  __shared__ bf16 Vs[128 * 72];      // [d][key], padded
  __shared__ bf16 Ps[4][16 * 72];    // per-wave [qrow][key], padded

  const int tid = threadIdx.x, w = tid >> 6, lane = tid & 63;
  const int quad = lane >> 4, col = lane & 15;
  const int q0 = blockIdx.x * 64;
  const int h = blockIdx.y, b = blockIdx.z;
  const int kvh = h / (NHEADS / NKV);
  const bf16* Qg = Q + (((size_t)b * NHEADS + h) * SEQ + q0) * HD;
  const bf16* Kg = K + ((size_t)b * NKV + kvh) * SEQ * HD;
  const bf16* Vg = Vt + ((size_t)b * NKV + kvh) * HD * SEQ;

#pragma unroll
  for (int i = 0; i < 4; i++) {
    int e = i * 2048 + tid * 8;
    int r = e >> 7, cc = e & 127;
    *(bf16x8*)&Qs[r * 136 + cc] = *(const bf16x8*)&Qg[(size_t)r * HD + cc];
  }

  f32x4 o[8];
#pragma unroll
  for (int nt = 0; nt < 8; nt++) { f32x4 z = {0.f, 0.f, 0.f, 0.f}; o[nt] = z; }
  float mi[4] = {-1e30f, -1e30f, -1e30f, -1e30f};
  float li[4] = {0.f, 0.f, 0.f, 0.f};

  const int nkt = (q0 >> 6) + 1;
  for (int kt = 0; kt < nkt; kt++) {
    const int kt0 = kt * 64;
    __syncthreads();
#pragma unroll
    for (int i = 0; i < 4; i++) {
      int e = i * 2048 + tid * 8;
      int r = e >> 7, cc = e & 127;
      *(bf16x8*)&Ks[r * 136 + cc] = *(const bf16x8*)&Kg[(size_t)(kt0 + r) * HD + cc];
      int dd = e >> 6, c2 = e & 63;
      *(bf16x8*)&Vs[dd * 72 + c2] = *(const bf16x8*)&Vg[(size_t)dd * SEQ + kt0 + c2];
    }
    __syncthreads();

    // S = Q K^T  (wave: 16 q rows x 64 keys)
    f32x4 sc[4];
#pragma unroll
    for (int j = 0; j < 4; j++) { f32x4 z = {0.f, 0.f, 0.f, 0.f}; sc[j] = z; }
#pragma unroll
    for (int kc = 0; kc < 4; kc++) {
      bf16x8 aq = *(const bf16x8*)&Qs[(w * 16 + col) * 136 + kc * 32 + quad * 8];
#pragma unroll
      for (int j = 0; j < 4; j++) {
        bf16x8 bk = *(const bf16x8*)&Ks[(j * 16 + col) * 136 + kc * 32 + quad * 8];
        sc[j] = __builtin_amdgcn_mfma_f32_16x16x32_bf16(aq, bk, sc[j], 0, 0, 0);
      }
    }

    // online softmax per row (rows live in 16-lane groups: row = quad*4+r, col = lane&15)
    float alpha[4];
#pragma unroll
    for (int r = 0; r < 4; r++) {
      int qrow = q0 + w * 16 + quad * 4 + r;
      float v[4];
      float tmax = -1e30f;
#pragma unroll
      for (int j = 0; j < 4; j++) {
        int key = kt0 + j * 16 + col;
        float x = sc[j][r] * SCALING + (key > qrow ? -1e9f : 0.0f);
        v[j] = x;
        tmax = fmaxf(tmax, x);
      }
#pragma unroll
      for (int mk = 8; mk >= 1; mk >>= 1) tmax = fmaxf(tmax, __shfl_xor(tmax, mk, 64));
      float mnew = fmaxf(mi[r], tmax);
      alpha[r] = exp2f((mi[r] - mnew) * L2E);
      float rs = 0.f;
#pragma unroll
      for (int j = 0; j < 4; j++) {
        float p = exp2f((v[j] - mnew) * L2E);
        rs += p;
        Ps[w][(quad * 4 + r) * 72 + j * 16 + col] = (bf16)p;
      }
#pragma unroll
      for (int mk = 8; mk >= 1; mk >>= 1) rs += __shfl_xor(rs, mk, 64);
      li[r] = li[r] * alpha[r] + rs;
      mi[r] = mnew;
    }
#pragma unroll
    for (int nt = 0; nt < 8; nt++)
#pragma unroll
      for (int r = 0; r < 4; r++) o[nt][r] *= alpha[r];

    // O += P V   (P: A-layout from LDS; V: B-layout from Vs[d][key])
#pragma unroll
    for (int ks = 0; ks < 2; ks++) {
      bf16x8 ap = *(const bf16x8*)&Ps[w][col * 72 + ks * 32 + quad * 8];
#pragma unroll
      for (int nt = 0; nt < 8; nt++) {
        bf16x8 bv = *(const bf16x8*)&Vs[(nt * 16 + col) * 72 + ks * 32 + quad * 8];
        o[nt] = __builtin_amdgcn_mfma_f32_16x16x32_bf16(ap, bv, o[nt], 0, 0, 0);
      }
    }
  }

  // epilogue: attn[b][s][h*128+d] bf16
  bf16* dst = attn + ((size_t)b * SEQ + q0 + w * 16) * HIDDEN + h * HD;
#pragma unroll
  for (int nt = 0; nt < 8; nt++)
#pragma unroll
    for (int r = 0; r < 4; r++) {
      float val = o[nt][r] / li[r];
      dst[(size_t)(quad * 4 + r) * HIDDEN + nt * 16 + col] = (bf16)val;
    }
}

extern "C" void kernel_launch(void* const* d_in, const int* in_sizes, int n_in,
                              void* d_out, int out_size, void* d_ws, size_t ws_size,
                              hipStream_t stream) {
  const float* hidden = (const float*)d_in[0];
  const float* cosp   = (const float*)d_in[1];
  const float* sinp   = (const float*)d_in[2];
  // d_in[3] attention_mask: pure causal, recomputed in-kernel
  const float* Wq = (const float*)d_in[4];
  const float* bq = (const float*)d_in[5];
  const float* Wk = (const float*)d_in[6];
  const float* bk = (const float*)d_in[7];
  const float* Wv = (const float*)d_in[8];
  const float* bv = (const float*)d_in[9];
  const float* Wo = (const float*)d_in[10];
  float* out = (float*)d_out;

  char* ws = (char*)d_ws;
  size_t off = 0;
  auto alloc = [&](size_t bytes) {
    char* p = ws + off;
    off += (bytes + 255) & ~(size_t)255;
    return p;
  };
  const size_t M = 4096;
  bf16* hb  = (bf16*)alloc(M * HIDDEN * 2);            // hidden bf16; reused as attn buffer
  bf16* wqb = (bf16*)alloc((size_t)3584 * 3584 * 2);
  bf16* wkb = (bf16*)alloc((size_t)512 * 3584 * 2);
  bf16* wvb = (bf16*)alloc((size_t)512 * 3584 * 2);
  bf16* wob = (bf16*)alloc((size_t)3584 * 3584 * 2);
  bf16* Qb  = (bf16*)alloc((size_t)2 * NHEADS * SEQ * HD * 2);
  bf16* Kb  = (bf16*)alloc((size_t)2 * NKV * SEQ * HD * 2);
  bf16* Vb  = (bf16*)alloc((size_t)2 * NKV * SEQ * HD * 2);
  bf16* Vt  = (bf16*)alloc((size_t)2 * NKV * SEQ * HD * 2);
  bf16* attn = hb;  // hidden dead after QKV GEMM

  f2bf_kernel<<<(4096 * 3584 / 8 + 255) / 256, 256, 0, stream>>>(hidden, hb, 4096 * 3584 / 8);
  f2bf_kernel<<<(3584 * 3584 / 8 + 255) / 256, 256, 0, stream>>>(Wq, wqb, 3584 * 3584 / 8);
  f2bf_kernel<<<(512 * 3584 / 8 + 255) / 256, 256, 0, stream>>>(Wk, wkb, 512 * 3584 / 8);
  f2bf_kernel<<<(512 * 3584 / 8 + 255) / 256, 256, 0, stream>>>(Wv, wvb, 512 * 3584 / 8);
  f2bf_kernel<<<(3584 * 3584 / 8 + 255) / 256, 256, 0, stream>>>(Wo, wob, 3584 * 3584 / 8);

  gemm_kernel<1><<<dim3(36, 32), 256, 0, stream>>>(hb, wqb, wkb, wvb, bq, bk, bv,
                                                   nullptr, Qb, Kb, Vb);
  rope_kernel<<<2 * NHEADS * SEQ * 16 / 256, 256, 0, stream>>>(Qb, cosp, sinp, NHEADS);
  rope_kernel<<<2 * NKV * SEQ * 16 / 256, 256, 0, stream>>>(Kb, cosp, sinp, NKV);
  transpose_kernel<<<dim3(64, 4, 8), dim3(32, 8), 0, stream>>>(Vb, Vt);
  flash_kernel<<<dim3(32, 28, 2), 256, 0, stream>>>(Qb, Kb, Vt, attn);
  gemm_kernel<0><<<dim3(28, 32), 256, 0, stream>>>(attn, wob, nullptr, nullptr,
                                                   nullptr, nullptr, nullptr,
                                                   out, nullptr, nullptr, nullptr);
}

// Round 2
// 805.695 us; speedup vs baseline: 1.1104x; 1.1104x over previous
//
#include <hip/hip_runtime.h>

typedef __bf16 bf16;
typedef __bf16 bf16x8 __attribute__((ext_vector_type(8)));
typedef __bf16 bf16x4 __attribute__((ext_vector_type(4)));
typedef float  f32x4  __attribute__((ext_vector_type(4)));

#define SEQ     2048
#define HIDDEN  3584
#define NHEADS  28
#define NKV     4
#define HD      128
#define SCALING 0.08838834764831845f
#define L2E     1.44269504088896341f
#define QSCALE  (SCALING * L2E)

typedef __attribute__((address_space(1))) void gvoid;
typedef __attribute__((address_space(3))) void lvoid;

__device__ __forceinline__ void gl_lds16(const void* g, void* l) {
  __builtin_amdgcn_global_load_lds((gvoid*)g, (lvoid*)l, 16, 0, 0);
}

// ---------------- fp32 -> bf16 convert ----------------
__global__ void f2bf_kernel(const float* __restrict__ in, bf16* __restrict__ out, int n8) {
  int i = blockIdx.x * 256 + threadIdx.x;
  if (i >= n8) return;
  const f32x4* p = (const f32x4*)(in + (size_t)i * 8);
  f32x4 x = p[0], y = p[1];
  bf16x8 o;
  o[0] = (bf16)x[0]; o[1] = (bf16)x[1]; o[2] = (bf16)x[2]; o[3] = (bf16)x[3];
  o[4] = (bf16)y[0]; o[5] = (bf16)y[1]; o[6] = (bf16)y[2]; o[7] = (bf16)y[3];
  *(bf16x8*)(out + (size_t)i * 8) = o;
}

// ---------------- NT GEMM: C[m][n] = sum_k A[m][k] * W[n][k] (+bias) ----------------
// MODE 0: plain fp32 out [M][3584] (output projection, no bias)
// MODE 1: fused QKV, N=4608; scatter bf16 into Q[B,28,S,128] / K,V[B,4,S,128] with bias
//         Q additionally scaled by QSCALE (folded softmax scaling, commutes with RoPE)
template <int MODE>
__global__ __launch_bounds__(256, 2) void gemm_kernel(
    const bf16* __restrict__ A,
    const bf16* __restrict__ W0, const bf16* __restrict__ W1, const bf16* __restrict__ W2,
    const float* __restrict__ b0, const float* __restrict__ b1, const float* __restrict__ b2,
    float* __restrict__ outF,
    bf16* __restrict__ Qb, bf16* __restrict__ Kb, bf16* __restrict__ Vb) {
  __shared__ bf16 As[128 * 32];
  __shared__ bf16 Bs[128 * 32];
  const int tid = threadIdx.x;
  const int w = tid >> 6, lane = tid & 63;
  const int wm = (w >> 1) * 64, wn = (w & 1) * 64;
  const int m0 = blockIdx.y * 128;
  const int n0 = blockIdx.x * 128;
  const int K = HIDDEN;

  const bf16* Bsrc;
  int nbase;
  if (MODE == 0) { Bsrc = W0; nbase = 0; }
  else {
    if (n0 < 3584)      { Bsrc = W0; nbase = 0; }
    else if (n0 < 4096) { Bsrc = W1; nbase = 3584; }
    else                { Bsrc = W2; nbase = 4096; }
  }
  const int bn0 = n0 - nbase;

  f32x4 acc[4][4];
#pragma unroll
  for (int i = 0; i < 4; i++)
#pragma unroll
    for (int j = 0; j < 4; j++) { f32x4 z = {0.f, 0.f, 0.f, 0.f}; acc[i][j] = z; }

  const int srow = lane >> 2;          // 0..15 within 1KB chunk
  const int scol = (lane & 3) * 8;     // element col offset
  const int mr = lane & 15, kq = (lane >> 4) * 8;

  for (int k0 = 0; k0 < K; k0 += 32) {
    __syncthreads();
#pragma unroll
    for (int c = 0; c < 2; c++) {
      int chunk = w * 2 + c;
      int row = chunk * 16 + srow;
      gl_lds16(&A[(size_t)(m0 + row) * K + k0 + scol], &As[chunk * 512]);
      gl_lds16(&Bsrc[(size_t)(bn0 + row) * K + k0 + scol], &Bs[chunk * 512]);
    }
    __syncthreads();
    bf16x8 a[4], b[4];
#pragma unroll
    for (int i = 0; i < 4; i++) a[i] = *(const bf16x8*)&As[(wm + i * 16 + mr) * 32 + kq];
#pragma unroll
    for (int j = 0; j < 4; j++) b[j] = *(const bf16x8*)&Bs[(wn + j * 16 + mr) * 32 + kq];
#pragma unroll
    for (int i = 0; i < 4; i++)
#pragma unroll
      for (int j = 0; j < 4; j++)
        acc[i][j] = __builtin_amdgcn_mfma_f32_16x16x32_bf16(a[i], b[j], acc[i][j], 0, 0, 0);
  }

  const int quad = lane >> 4, col = lane & 15;
  if (MODE == 0) {
#pragma unroll
    for (int i = 0; i < 4; i++)
#pragma unroll
      for (int j = 0; j < 4; j++) {
        int n = n0 + wn + j * 16 + col;
#pragma unroll
        for (int r = 0; r < 4; r++) {
          int m = m0 + wm + i * 16 + quad * 4 + r;
          outF[(size_t)m * 3584 + n] = acc[i][j][r];
        }
      }
  } else {
    bf16* dst; int H; const float* bias; float mult;
    if (n0 < 3584)      { dst = Qb; H = NHEADS; bias = b0; mult = QSCALE; }
    else if (n0 < 4096) { dst = Kb; H = NKV;    bias = b1; mult = 1.0f; }
    else                { dst = Vb; H = NKV;    bias = b2; mult = 1.0f; }
#pragma unroll
    for (int j = 0; j < 4; j++) {
      int nl = bn0 + wn + j * 16 + col;
      float bb = bias[nl];
      int hh = nl >> 7, d = nl & 127;
#pragma unroll
      for (int i = 0; i < 4; i++)
#pragma unroll
        for (int r = 0; r < 4; r++) {
          int m = m0 + wm + i * 16 + quad * 4 + r;
          int bidx = m >> 11, s = m & 2047;
          dst[(((size_t)bidx * H + hh) * SEQ + s) * HD + d] = (bf16)((acc[i][j][r] + bb) * mult);
        }
    }
  }
}

// ---------------- RoPE (in place, bf16) ----------------
__global__ void rope_kernel(bf16* __restrict__ X, const float* __restrict__ cosp,
                            const float* __restrict__ sinp, int nheads) {
  int idx = blockIdx.x * 256 + threadIdx.x;
  int dg = idx & 15;            // d = dg*4 in [0,64)
  int s = (idx >> 4) & 2047;
  int bh = idx >> 15;
  int b = bh / nheads;
  int d = dg * 4;
  f32x4 c = *(const f32x4*)&cosp[((size_t)b * SEQ + s) * HD + d];
  f32x4 sn = *(const f32x4*)&sinp[((size_t)b * SEQ + s) * HD + d];
  bf16* p = X + ((size_t)bh * SEQ + s) * HD + d;
  bf16x4 lo = *(bf16x4*)p;
  bf16x4 hi = *(bf16x4*)(p + 64);
  bf16x4 nlo, nhi;
#pragma unroll
  for (int i = 0; i < 4; i++) {
    float l = (float)lo[i], h = (float)hi[i];
    nlo[i] = (bf16)(l * c[i] - h * sn[i]);
    nhi[i] = (bf16)(h * c[i] + l * sn[i]);
  }
  *(bf16x4*)p = nlo;
  *(bf16x4*)(p + 64) = nhi;
}

// ---------------- V transpose per head: [S][D] -> [D][S] ----------------
__global__ void transpose_kernel(const bf16* __restrict__ V, bf16* __restrict__ Vt) {
  __shared__ bf16 t[32][33];
  int head = blockIdx.z;
  int s0 = blockIdx.x * 32, d0 = blockIdx.y * 32;
  const bf16* src = V + (size_t)head * SEQ * HD;
  bf16* dst = Vt + (size_t)head * HD * SEQ;
#pragma unroll
  for (int i = 0; i < 4; i++)
    t[threadIdx.y + i * 8][threadIdx.x] =
        src[(size_t)(s0 + threadIdx.y + i * 8) * HD + d0 + threadIdx.x];
  __syncthreads();
#pragma unroll
  for (int i = 0; i < 4; i++)
    dst[(size_t)(d0 + threadIdx.y + i * 8) * SEQ + s0 + threadIdx.x] =
        t[threadIdx.x][threadIdx.y + i * 8];
}

// ---------------- Flash attention ----------------
// grid (S/128, 28, 2) with x REVERSED (heavy q-tiles first); block 512 = 8 waves;
// wave w owns q rows [q0+16w, q0+16w+16). Q fragments in registers.
// LDS XOR-swizzled at 16B granularity: conflict-free + global_load_lds staging.
__global__ __launch_bounds__(512, 4) void flash_kernel(
    const bf16* __restrict__ Q, const bf16* __restrict__ K,
    const bf16* __restrict__ Vt, bf16* __restrict__ attn) {
  __shared__ bf16 Ks[64 * 128];      // [key][16B-chunk ^ (key&15)]
  __shared__ bf16 Vs[128 * 64];      // [d][16B-chunk ^ (d&7)]
  __shared__ bf16 Ps[8][16 * 64];    // per-wave [qrow][16B-chunk ^ (qrow&7)]

  const int tid = threadIdx.x, w = tid >> 6, lane = tid & 63;
  const int quad = lane >> 4, col = lane & 15;
  const int qt = (int)gridDim.x - 1 - (int)blockIdx.x;
  const int q0 = qt * 128;
  const int h = blockIdx.y, b = blockIdx.z;
  const int kvh = h / (NHEADS / NKV);
  const bf16* Qg = Q + (((size_t)b * NHEADS + h) * SEQ + q0 + w * 16) * HD;
  const bf16* Kg = K + ((size_t)b * NKV + kvh) * SEQ * HD;
  const bf16* Vg = Vt + ((size_t)b * NKV + kvh) * HD * SEQ;

  // Q fragments (A-layout): m = col, k = kc*32 + quad*8 + 0..7
  bf16x8 aq[4];
#pragma unroll
  for (int kc = 0; kc < 4; kc++)
    aq[kc] = *(const bf16x8*)&Qg[(size_t)col * HD + kc * 32 + quad * 8];

  f32x4 o[8];
#pragma unroll
  for (int nt = 0; nt < 8; nt++) { f32x4 z = {0.f, 0.f, 0.f, 0.f}; o[nt] = z; }
  float mi[4] = {-1e30f, -1e30f, -1e30f, -1e30f};
  float li[4] = {0.f, 0.f, 0.f, 0.f};   // per-LANE partial sums; reduced in epilogue

  const int nkt = q0 / 64 + 2;
  for (int kt = 0; kt < nkt; kt++) {
    const int kt0 = kt * 64;
    __syncthreads();
    // async stage K (64x128) and V (128x64) via global_load_lds, swizzled source
#pragma unroll
    for (int t = 0; t < 2; t++) {
      int br = (w * 2 + t) * 4;                 // Ks: 4 key-rows per 1KB wave-instr
      int kr = br + (lane >> 4);
      int kc2 = (lane & 15) ^ (kr & 15);
      gl_lds16(&Kg[(size_t)(kt0 + kr) * HD + kc2 * 8], &Ks[br * 128]);
      int bd = (w * 2 + t) * 8;                 // Vs: 8 d-rows per 1KB wave-instr
      int dd = bd + (lane >> 3);
      int vc = (lane & 7) ^ (dd & 7);
      gl_lds16(&Vg[(size_t)dd * SEQ + kt0 + vc * 8], &Vs[bd * 64]);
    }
    __syncthreads();

    // S = Q K^T  (wave: 16 q rows x 64 keys); scores pre-scaled by QSCALE via Q
    f32x4 sc[4];
#pragma unroll
    for (int j = 0; j < 4; j++) { f32x4 z = {0.f, 0.f, 0.f, 0.f}; sc[j] = z; }
#pragma unroll
    for (int kc = 0; kc < 4; kc++) {
#pragma unroll
      for (int j = 0; j < 4; j++) {
        bf16x8 bk = *(const bf16x8*)&Ks[(j * 16 + col) * 128 + (((kc * 4 + quad) ^ col) << 3)];
        sc[j] = __builtin_amdgcn_mfma_f32_16x16x32_bf16(aq[kc], bk, sc[j], 0, 0, 0);
      }
    }

    // online softmax (base-2 domain); row = quad*4+r lives in 16 lanes (col)
    float alpha[4];
#pragma unroll
    for (int r = 0; r < 4; r++) {
      int qrow = q0 + w * 16 + quad * 4 + r;
      float v[4];
      float tmax = -1e30f;
#pragma unroll
      for (int j = 0; j < 4; j++) {
        int key = kt0 + j * 16 + col;
        float x = sc[j][r] + (key > qrow ? -1e9f : 0.0f);
        v[j] = x;
        tmax = fmaxf(tmax, x);
      }
#pragma unroll
      for (int mk = 8; mk >= 1; mk >>= 1) tmax = fmaxf(tmax, __shfl_xor(tmax, mk, 64));
      float mnew = fmaxf(mi[r], tmax);
      alpha[r] = exp2f(mi[r] - mnew);
      int row = quad * 4 + r;
      float rs = 0.f;
#pragma unroll
      for (int j = 0; j < 4; j++) {
        float p = exp2f(v[j] - mnew);
        rs += p;
        Ps[w][row * 64 + ((((j * 2 + (col >> 3)) ^ (row & 7)) << 3) | (col & 7))] = (bf16)p;
      }
      li[r] = li[r] * alpha[r] + rs;
      mi[r] = mnew;
    }
#pragma unroll
    for (int nt = 0; nt < 8; nt++)
#pragma unroll
      for (int r = 0; r < 4; r++) o[nt][r] *= alpha[r];

    // O += P V   (P: A-layout, per-wave Ps; V: B-layout from Vs[d][key])
#pragma unroll
    for (int ks = 0; ks < 2; ks++) {
      bf16x8 ap = *(const bf16x8*)&Ps[w][col * 64 + (((ks * 4 + quad) ^ (col & 7)) << 3)];
#pragma unroll
      for (int nt = 0; nt < 8; nt++) {
        bf16x8 bv = *(const bf16x8*)&Vs[(nt * 16 + col) * 64 + (((ks * 4 + quad) ^ (col & 7)) << 3)];
        o[nt] = __builtin_amdgcn_mfma_f32_16x16x32_bf16(ap, bv, o[nt], 0, 0, 0);
      }
    }
  }

  // epilogue: reduce per-lane l partials across the 16-lane row group, then store
  float rinv[4];
#pragma unroll
  for (int r = 0; r < 4; r++) {
    float rs = li[r];
#pragma unroll
    for (int mk = 1; mk <= 8; mk <<= 1) rs += __shfl_xor(rs, mk, 64);
    rinv[r] = 1.0f / rs;
  }
  bf16* dst = attn + ((size_t)(b * SEQ + q0 + w * 16)) * HIDDEN + h * HD;
#pragma unroll
  for (int nt = 0; nt < 8; nt++)
#pragma unroll
    for (int r = 0; r < 4; r++)
      dst[(size_t)(quad * 4 + r) * HIDDEN + nt * 16 + col] = (bf16)(o[nt][r] * rinv[r]);
}

extern "C" void kernel_launch(void* const* d_in, const int* in_sizes, int n_in,
                              void* d_out, int out_size, void* d_ws, size_t ws_size,
                              hipStream_t stream) {
  const float* hidden = (const float*)d_in[0];
  const float* cosp   = (const float*)d_in[1];
  const float* sinp   = (const float*)d_in[2];
  // d_in[3] attention_mask: pure causal, recomputed in-kernel
  const float* Wq = (const float*)d_in[4];
  const float* bq = (const float*)d_in[5];
  const float* Wk = (const float*)d_in[6];
  const float* bk = (const float*)d_in[7];
  const float* Wv = (const float*)d_in[8];
  const float* bv = (const float*)d_in[9];
  const float* Wo = (const float*)d_in[10];
  float* out = (float*)d_out;

  char* ws = (char*)d_ws;
  size_t off = 0;
  auto alloc = [&](size_t bytes) {
    char* p = ws + off;
    off += (bytes + 255) & ~(size_t)255;
    return p;
  };
  const size_t M = 4096;
  bf16* hb  = (bf16*)alloc(M * HIDDEN * 2);            // hidden bf16; reused as attn buffer
  bf16* wqb = (bf16*)alloc((size_t)3584 * 3584 * 2);
  bf16* wkb = (bf16*)alloc((size_t)512 * 3584 * 2);
  bf16* wvb = (bf16*)alloc((size_t)512 * 3584 * 2);
  bf16* wob = (bf16*)alloc((size_t)3584 * 3584 * 2);
  bf16* Qb  = (bf16*)alloc((size_t)2 * NHEADS * SEQ * HD * 2);
  bf16* Kb  = (bf16*)alloc((size_t)2 * NKV * SEQ * HD * 2);
  bf16* Vb  = (bf16*)alloc((size_t)2 * NKV * SEQ * HD * 2);
  bf16* Vt  = (bf16*)alloc((size_t)2 * NKV * SEQ * HD * 2);
  bf16* attn = hb;  // hidden dead after QKV GEMM

  f2bf_kernel<<<(4096 * 3584 / 8 + 255) / 256, 256, 0, stream>>>(hidden, hb, 4096 * 3584 / 8);
  f2bf_kernel<<<(3584 * 3584 / 8 + 255) / 256, 256, 0, stream>>>(Wq, wqb, 3584 * 3584 / 8);
  f2bf_kernel<<<(512 * 3584 / 8 + 255) / 256, 256, 0, stream>>>(Wk, wkb, 512 * 3584 / 8);
  f2bf_kernel<<<(512 * 3584 / 8 + 255) / 256, 256, 0, stream>>>(Wv, wvb, 512 * 3584 / 8);
  f2bf_kernel<<<(3584 * 3584 / 8 + 255) / 256, 256, 0, stream>>>(Wo, wob, 3584 * 3584 / 8);

  gemm_kernel<1><<<dim3(36, 32), 256, 0, stream>>>(hb, wqb, wkb, wvb, bq, bk, bv,
                                                   nullptr, Qb, Kb, Vb);
  rope_kernel<<<2 * NHEADS * SEQ * 16 / 256, 256, 0, stream>>>(Qb, cosp, sinp, NHEADS);
  rope_kernel<<<2 * NKV * SEQ * 16 / 256, 256, 0, stream>>>(Kb, cosp, sinp, NKV);
  transpose_kernel<<<dim3(64, 4, 8), dim3(32, 8), 0, stream>>>(Vb, Vt);
  flash_kernel<<<dim3(16, 28, 2), 512, 0, stream>>>(Qb, Kb, Vt, attn);
  gemm_kernel<0><<<dim3(28, 32), 256, 0, stream>>>(attn, wob, nullptr, nullptr,
                                                   nullptr, nullptr, nullptr,
                                                   out, nullptr, nullptr, nullptr);
}

// Round 3
// 773.071 us; speedup vs baseline: 1.1573x; 1.0422x over previous
//
#include <hip/hip_runtime.h>

typedef __bf16 bf16;
typedef __bf16 bf16x8 __attribute__((ext_vector_type(8)));
typedef __bf16 bf16x4 __attribute__((ext_vector_type(4)));
typedef float  f32x4  __attribute__((ext_vector_type(4)));

#define SEQ     2048
#define HIDDEN  3584
#define NHEADS  28
#define NKV     4
#define HD      128
#define SCALING 0.08838834764831845f
#define L2E     1.44269504088896341f
#define QSCALE  (SCALING * L2E)

typedef __attribute__((address_space(1))) void gvoid;
typedef __attribute__((address_space(3))) void lvoid;

__device__ __forceinline__ void gl_lds16(const void* g, void* l) {
  __builtin_amdgcn_global_load_lds((gvoid*)g, (lvoid*)l, 16, 0, 0);
}

// ---------------- fp32 -> bf16 convert ----------------
__global__ void f2bf_kernel(const float* __restrict__ in, bf16* __restrict__ out, int n8) {
  int i = blockIdx.x * 256 + threadIdx.x;
  if (i >= n8) return;
  const f32x4* p = (const f32x4*)(in + (size_t)i * 8);
  f32x4 x = p[0], y = p[1];
  bf16x8 o;
  o[0] = (bf16)x[0]; o[1] = (bf16)x[1]; o[2] = (bf16)x[2]; o[3] = (bf16)x[3];
  o[4] = (bf16)y[0]; o[5] = (bf16)y[1]; o[6] = (bf16)y[2]; o[7] = (bf16)y[3];
  *(bf16x8*)(out + (size_t)i * 8) = o;
}

// ---------------- NT GEMM: C[m][n] = sum_k A[m][k] * W[n][k] (+bias) ----------------
template <int MODE>
__global__ __launch_bounds__(256, 2) void gemm_kernel(
    const bf16* __restrict__ A,
    const bf16* __restrict__ W0, const bf16* __restrict__ W1, const bf16* __restrict__ W2,
    const float* __restrict__ b0, const float* __restrict__ b1, const float* __restrict__ b2,
    float* __restrict__ outF,
    bf16* __restrict__ Qb, bf16* __restrict__ Kb, bf16* __restrict__ Vb) {
  __shared__ bf16 As[128 * 32];
  __shared__ bf16 Bs[128 * 32];
  const int tid = threadIdx.x;
  const int w = tid >> 6, lane = tid & 63;
  const int wm = (w >> 1) * 64, wn = (w & 1) * 64;
  const int m0 = blockIdx.y * 128;
  const int n0 = blockIdx.x * 128;
  const int K = HIDDEN;

  const bf16* Bsrc;
  int nbase;
  if (MODE == 0) { Bsrc = W0; nbase = 0; }
  else {
    if (n0 < 3584)      { Bsrc = W0; nbase = 0; }
    else if (n0 < 4096) { Bsrc = W1; nbase = 3584; }
    else                { Bsrc = W2; nbase = 4096; }
  }
  const int bn0 = n0 - nbase;

  f32x4 acc[4][4];
#pragma unroll
  for (int i = 0; i < 4; i++)
#pragma unroll
    for (int j = 0; j < 4; j++) { f32x4 z = {0.f, 0.f, 0.f, 0.f}; acc[i][j] = z; }

  const int srow = lane >> 2;
  const int scol = (lane & 3) * 8;
  const int mr = lane & 15, kq = (lane >> 4) * 8;

  for (int k0 = 0; k0 < K; k0 += 32) {
    __syncthreads();
#pragma unroll
    for (int c = 0; c < 2; c++) {
      int chunk = w * 2 + c;
      int row = chunk * 16 + srow;
      gl_lds16(&A[(size_t)(m0 + row) * K + k0 + scol], &As[chunk * 512]);
      gl_lds16(&Bsrc[(size_t)(bn0 + row) * K + k0 + scol], &Bs[chunk * 512]);
    }
    __syncthreads();
    bf16x8 a[4], b[4];
#pragma unroll
    for (int i = 0; i < 4; i++) a[i] = *(const bf16x8*)&As[(wm + i * 16 + mr) * 32 + kq];
#pragma unroll
    for (int j = 0; j < 4; j++) b[j] = *(const bf16x8*)&Bs[(wn + j * 16 + mr) * 32 + kq];
#pragma unroll
    for (int i = 0; i < 4; i++)
#pragma unroll
      for (int j = 0; j < 4; j++)
        acc[i][j] = __builtin_amdgcn_mfma_f32_16x16x32_bf16(a[i], b[j], acc[i][j], 0, 0, 0);
  }

  const int quad = lane >> 4, col = lane & 15;
  if (MODE == 0) {
#pragma unroll
    for (int i = 0; i < 4; i++)
#pragma unroll
      for (int j = 0; j < 4; j++) {
        int n = n0 + wn + j * 16 + col;
#pragma unroll
        for (int r = 0; r < 4; r++) {
          int m = m0 + wm + i * 16 + quad * 4 + r;
          outF[(size_t)m * 3584 + n] = acc[i][j][r];
        }
      }
  } else {
    bf16* dst; int H; const float* bias; float mult;
    if (n0 < 3584)      { dst = Qb; H = NHEADS; bias = b0; mult = QSCALE; }
    else if (n0 < 4096) { dst = Kb; H = NKV;    bias = b1; mult = 1.0f; }
    else                { dst = Vb; H = NKV;    bias = b2; mult = 1.0f; }
#pragma unroll
    for (int j = 0; j < 4; j++) {
      int nl = bn0 + wn + j * 16 + col;
      float bb = bias[nl];
      int hh = nl >> 7, d = nl & 127;
#pragma unroll
      for (int i = 0; i < 4; i++)
#pragma unroll
        for (int r = 0; r < 4; r++) {
          int m = m0 + wm + i * 16 + quad * 4 + r;
          int bidx = m >> 11, s = m & 2047;
          dst[(((size_t)bidx * H + hh) * SEQ + s) * HD + d] = (bf16)((acc[i][j][r] + bb) * mult);
        }
    }
  }
}

// ---------------- RoPE (in place, bf16) ----------------
__global__ void rope_kernel(bf16* __restrict__ X, const float* __restrict__ cosp,
                            const float* __restrict__ sinp, int nheads) {
  int idx = blockIdx.x * 256 + threadIdx.x;
  int dg = idx & 15;
  int s = (idx >> 4) & 2047;
  int bh = idx >> 15;
  int b = bh / nheads;
  int d = dg * 4;
  f32x4 c = *(const f32x4*)&cosp[((size_t)b * SEQ + s) * HD + d];
  f32x4 sn = *(const f32x4*)&sinp[((size_t)b * SEQ + s) * HD + d];
  bf16* p = X + ((size_t)bh * SEQ + s) * HD + d;
  bf16x4 lo = *(bf16x4*)p;
  bf16x4 hi = *(bf16x4*)(p + 64);
  bf16x4 nlo, nhi;
#pragma unroll
  for (int i = 0; i < 4; i++) {
    float l = (float)lo[i], h = (float)hi[i];
    nlo[i] = (bf16)(l * c[i] - h * sn[i]);
    nhi[i] = (bf16)(h * c[i] + l * sn[i]);
  }
  *(bf16x4*)p = nlo;
  *(bf16x4*)(p + 64) = nhi;
}

// ---------------- V transpose per head: [S][D] -> [D][S] ----------------
__global__ void transpose_kernel(const bf16* __restrict__ V, bf16* __restrict__ Vt) {
  __shared__ bf16 t[32][33];
  int head = blockIdx.z;
  int s0 = blockIdx.x * 32, d0 = blockIdx.y * 32;
  const bf16* src = V + (size_t)head * SEQ * HD;
  bf16* dst = Vt + (size_t)head * HD * SEQ;
#pragma unroll
  for (int i = 0; i < 4; i++)
    t[threadIdx.y + i * 8][threadIdx.x] =
        src[(size_t)(s0 + threadIdx.y + i * 8) * HD + d0 + threadIdx.x];
  __syncthreads();
#pragma unroll
  for (int i = 0; i < 4; i++)
    dst[(size_t)(d0 + threadIdx.y + i * 8) * SEQ + s0 + threadIdx.x] =
        t[threadIdx.x][threadIdx.y + i * 8];
}

__device__ __forceinline__ float vmax4(f32x4 a) {
  return fmaxf(fmaxf(a[0], a[1]), fmaxf(a[2], a[3]));
}

// ---------------- Flash attention (S^T formulation, reg-prefetch staging) ------
// grid (S/128, 28, 2), x reversed (heavy q-tiles first); block 512 = 8 waves.
// Wave w owns q rows [q0+16w, q0+16w+16); lane's q = col, keys live in-lane.
// S^T = K·Q^T (A=K rows, B=Q regs) -> softmax along in-lane keys (2 shuffles) ->
// O^T = V^T·P^T (A=Vs[d][key], B=Ps[q][key]).
__global__ __launch_bounds__(512, 4) void flash_kernel(
    const bf16* __restrict__ Q, const bf16* __restrict__ K,
    const bf16* __restrict__ Vt, bf16* __restrict__ attn) {
  __shared__ bf16 Ks[64 * 136];      // [key][d], padded stride 136 (bank-spread)
  __shared__ bf16 Vs[128 * 72];      // [d][key], padded stride 72
  __shared__ bf16 Ps[8][16 * 72];    // per-wave [q][key], padded stride 72

  const int tid = threadIdx.x, w = tid >> 6, lane = tid & 63;
  const int quad = lane >> 4, col = lane & 15;
  const int qt = (int)gridDim.x - 1 - (int)blockIdx.x;
  const int q0 = qt * 128;
  const int h = blockIdx.y, b = blockIdx.z;
  const int kvh = h / (NHEADS / NKV);
  const bf16* Qg = Q + (((size_t)b * NHEADS + h) * SEQ + q0 + w * 16) * HD;
  const bf16* Kg = K + ((size_t)b * NKV + kvh) * SEQ * HD;
  const bf16* Vg = Vt + ((size_t)b * NKV + kvh) * HD * SEQ;

  // Q fragment (B-operand): n = col (q row), k = kc*32 + quad*8 + 0..7
  bf16x8 aq[4];
#pragma unroll
  for (int kc = 0; kc < 4; kc++)
    aq[kc] = *(const bf16x8*)&Qg[(size_t)col * HD + kc * 32 + quad * 8];

  // staging assignment: K 64x128 (2 chunks/thread), V 128x64 (2 chunks/thread)
  const int kr0 = tid >> 4, kc0 = (tid & 15) * 8;
  const int vd0 = tid >> 3, vc0 = (tid & 7) * 8;

  // preload tile 0 into registers
  bf16x8 kg0 = *(const bf16x8*)&Kg[(size_t)kr0 * HD + kc0];
  bf16x8 kg1 = *(const bf16x8*)&Kg[(size_t)(kr0 + 32) * HD + kc0];
  bf16x8 vg0 = *(const bf16x8*)&Vg[(size_t)vd0 * SEQ + vc0];
  bf16x8 vg1 = *(const bf16x8*)&Vg[(size_t)(vd0 + 64) * SEQ + vc0];

  f32x4 o[8];
#pragma unroll
  for (int nt = 0; nt < 8; nt++) { f32x4 z = {0.f, 0.f, 0.f, 0.f}; o[nt] = z; }
  float mi = -1e30f, li = 0.f;     // per-lane: q = col, partial over this quad's keys
  const int myq = q0 + w * 16 + col;
  const int nkt = q0 / 64 + 2;

  for (int kt = 0; kt < nkt; kt++) {
    const int kt0 = kt * 64;
    __syncthreads();                               // prev tile consumers done
    *(bf16x8*)&Ks[kr0 * 136 + kc0] = kg0;
    *(bf16x8*)&Ks[(kr0 + 32) * 136 + kc0] = kg1;
    *(bf16x8*)&Vs[vd0 * 72 + vc0] = vg0;
    *(bf16x8*)&Vs[(vd0 + 64) * 72 + vc0] = vg1;
    __syncthreads();                               // tile kt visible
    if (kt + 1 < nkt) {                            // prefetch kt+1, overlaps compute
      const int n0 = kt0 + 64;
      kg0 = *(const bf16x8*)&Kg[(size_t)(n0 + kr0) * HD + kc0];
      kg1 = *(const bf16x8*)&Kg[(size_t)(n0 + kr0 + 32) * HD + kc0];
      vg0 = *(const bf16x8*)&Vg[(size_t)vd0 * SEQ + n0 + vc0];
      vg1 = *(const bf16x8*)&Vg[(size_t)(vd0 + 64) * SEQ + n0 + vc0];
    }
    if (kt0 <= q0 + w * 16 + 15) {                 // wave-level tile skip
      // S^T = K Q^T : lane gets q=col, keys j*16 + quad*4 + r
      f32x4 sc[4];
#pragma unroll
      for (int j = 0; j < 4; j++) { f32x4 z = {0.f, 0.f, 0.f, 0.f}; sc[j] = z; }
#pragma unroll
      for (int kc = 0; kc < 4; kc++)
#pragma unroll
        for (int j = 0; j < 4; j++) {
          bf16x8 ak = *(const bf16x8*)&Ks[(j * 16 + col) * 136 + kc * 32 + quad * 8];
          sc[j] = __builtin_amdgcn_mfma_f32_16x16x32_bf16(ak, aq[kc], sc[j], 0, 0, 0);
        }
      if (kt0 + 63 > q0 + w * 16) {                // single diagonal tile per wave
        const int kb = kt0 + quad * 4;
#pragma unroll
        for (int j = 0; j < 4; j++)
#pragma unroll
          for (int r = 0; r < 4; r++)
            if (kb + j * 16 + r > myq) sc[j][r] = -1e30f;
      }
      // row max: 15 in-lane ops + 2 shuffles (across quads)
      f32x4 t01, t23;
#pragma unroll
      for (int r = 0; r < 4; r++) { t01[r] = fmaxf(sc[0][r], sc[1][r]); t23[r] = fmaxf(sc[2][r], sc[3][r]); }
      float tm = fmaxf(vmax4(t01), vmax4(t23));
      tm = fmaxf(tm, __shfl_xor(tm, 16, 64));
      tm = fmaxf(tm, __shfl_xor(tm, 32, 64));
      float mnew = fmaxf(mi, tm);
      float alpha = exp2f(mi - mnew);
      mi = mnew;
      float rs = 0.f;
#pragma unroll
      for (int j = 0; j < 4; j++) {
        f32x4 pe;
#pragma unroll
        for (int r = 0; r < 4; r++) pe[r] = exp2f(sc[j][r] - mnew);
        rs += (pe[0] + pe[1]) + (pe[2] + pe[3]);
        bf16x4 pb;
#pragma unroll
        for (int r = 0; r < 4; r++) pb[r] = (bf16)pe[r];
        *(bf16x4*)&Ps[w][col * 72 + j * 16 + quad * 4] = pb;   // 1 ds_write_b64
      }
      li = li * alpha + rs;
#pragma unroll
      for (int nt = 0; nt < 8; nt++) {
#pragma unroll
        for (int r = 0; r < 4; r++) o[nt][r] *= alpha;
      }
      // O^T += V^T P^T
#pragma unroll
      for (int ks = 0; ks < 2; ks++) {
        bf16x8 bp = *(const bf16x8*)&Ps[w][col * 72 + ks * 32 + quad * 8];
#pragma unroll
        for (int nt = 0; nt < 8; nt++) {
          bf16x8 av = *(const bf16x8*)&Vs[(nt * 16 + col) * 72 + ks * 32 + quad * 8];
          o[nt] = __builtin_amdgcn_mfma_f32_16x16x32_bf16(av, bp, o[nt], 0, 0, 0);
        }
      }
    }
  }

  // epilogue: complete l across quads, store O^T: lane q=col, d = nt*16+quad*4+r
  li += __shfl_xor(li, 16, 64);
  li += __shfl_xor(li, 32, 64);
  float rinv = 1.0f / li;
  bf16* dst = attn + ((size_t)b * SEQ + q0 + w * 16 + col) * HIDDEN + h * HD + quad * 4;
#pragma unroll
  for (int nt = 0; nt < 8; nt++) {
    bf16x4 ob;
#pragma unroll
    for (int r = 0; r < 4; r++) ob[r] = (bf16)(o[nt][r] * rinv);
    *(bf16x4*)&dst[nt * 16] = ob;
  }
}

extern "C" void kernel_launch(void* const* d_in, const int* in_sizes, int n_in,
                              void* d_out, int out_size, void* d_ws, size_t ws_size,
                              hipStream_t stream) {
  const float* hidden = (const float*)d_in[0];
  const float* cosp   = (const float*)d_in[1];
  const float* sinp   = (const float*)d_in[2];
  const float* Wq = (const float*)d_in[4];
  const float* bq = (const float*)d_in[5];
  const float* Wk = (const float*)d_in[6];
  const float* bk = (const float*)d_in[7];
  const float* Wv = (const float*)d_in[8];
  const float* bv = (const float*)d_in[9];
  const float* Wo = (const float*)d_in[10];
  float* out = (float*)d_out;

  char* ws = (char*)d_ws;
  size_t off = 0;
  auto alloc = [&](size_t bytes) {
    char* p = ws + off;
    off += (bytes + 255) & ~(size_t)255;
    return p;
  };
  const size_t M = 4096;
  bf16* hb  = (bf16*)alloc(M * HIDDEN * 2);
  bf16* wqb = (bf16*)alloc((size_t)3584 * 3584 * 2);
  bf16* wkb = (bf16*)alloc((size_t)512 * 3584 * 2);
  bf16* wvb = (bf16*)alloc((size_t)512 * 3584 * 2);
  bf16* wob = (bf16*)alloc((size_t)3584 * 3584 * 2);
  bf16* Qb  = (bf16*)alloc((size_t)2 * NHEADS * SEQ * HD * 2);
  bf16* Kb  = (bf16*)alloc((size_t)2 * NKV * SEQ * HD * 2);
  bf16* Vb  = (bf16*)alloc((size_t)2 * NKV * SEQ * HD * 2);
  bf16* Vt  = (bf16*)alloc((size_t)2 * NKV * SEQ * HD * 2);
  bf16* attn = hb;  // hidden dead after QKV GEMM

  f2bf_kernel<<<(4096 * 3584 / 8 + 255) / 256, 256, 0, stream>>>(hidden, hb, 4096 * 3584 / 8);
  f2bf_kernel<<<(3584 * 3584 / 8 + 255) / 256, 256, 0, stream>>>(Wq, wqb, 3584 * 3584 / 8);
  f2bf_kernel<<<(512 * 3584 / 8 + 255) / 256, 256, 0, stream>>>(Wk, wkb, 512 * 3584 / 8);
  f2bf_kernel<<<(512 * 3584 / 8 + 255) / 256, 256, 0, stream>>>(Wv, wvb, 512 * 3584 / 8);
  f2bf_kernel<<<(3584 * 3584 / 8 + 255) / 256, 256, 0, stream>>>(Wo, wob, 3584 * 3584 / 8);

  gemm_kernel<1><<<dim3(36, 32), 256, 0, stream>>>(hb, wqb, wkb, wvb, bq, bk, bv,
                                                   nullptr, Qb, Kb, Vb);
  rope_kernel<<<2 * NHEADS * SEQ * 16 / 256, 256, 0, stream>>>(Qb, cosp, sinp, NHEADS);
  rope_kernel<<<2 * NKV * SEQ * 16 / 256, 256, 0, stream>>>(Kb, cosp, sinp, NKV);
  transpose_kernel<<<dim3(64, 4, 8), dim3(32, 8), 0, stream>>>(Vb, Vt);
  flash_kernel<<<dim3(16, 28, 2), 512, 0, stream>>>(Qb, Kb, Vt, attn);
  gemm_kernel<0><<<dim3(28, 32), 256, 0, stream>>>(attn, wob, nullptr, nullptr,
                                                   nullptr, nullptr, nullptr,
                                                   out, nullptr, nullptr, nullptr);
}